// Round 12
// baseline (178.325 us; speedup 1.0000x reference)
//
#include <hip/hip_runtime.h>

#define KN 32      // neighbors
#define NF 128     // feature dim
#define NH 4       // heads
#define HD 256     // H*D
#define NC 40      // classes
#define NPW 8      // nodes per wave
#define WPB 4      // waves per block -> 32 nodes per block
#define NPB2 (NPW * WPB)

// ws layout (floats): [0,512)=w_src[h][f], [512,1024)=w_dst[h][f],
//   [1024,21504)=MT[cls][h*128+f], [21504,21504+4*n)=ei[n][h]
#define WS_WSRC 0
#define WS_WDST 512
#define WS_MT   1024
#define WS_EI   (1024 + NC * 512)

static __device__ __forceinline__ unsigned short bf16_of(float x) {
    union { float f; unsigned u; } v; v.f = x;
    unsigned r = v.u + 0x7FFFu + ((v.u >> 16) & 1u);   // RNE
    return (unsigned short)(r >> 16);
}
static __device__ __forceinline__ float f_of_bf16(unsigned short b) {
    union { unsigned u; float f; } v; v.u = ((unsigned)b) << 16; return v.f;
}

// merged prep: blocks 0-3 -> w_src/w_dst; blocks 4.. -> MT
__global__ void gat_prep_wm(const float* __restrict__ W,
                            const float* __restrict__ a_src,
                            const float* __restrict__ a_dst,
                            const float* __restrict__ cls_w,
                            float* __restrict__ ws)
{
    if (blockIdx.x < 4) {
        int g = blockIdx.x * 256 + threadIdx.x;
        int which = g >> 9, h = (g >> 7) & 3, f = g & 127;
        const float* a = which ? a_dst : a_src;
        float s = 0.f;
        #pragma unroll 8
        for (int d = 0; d < 64; ++d)
            s = fmaf(W[f * HD + h * 64 + d], a[h * 64 + d], s);
        ws[g] = s;
    } else {
        int g = (blockIdx.x - 4) * 256 + threadIdx.x;
        if (g >= NC * 512) return;
        int cls = g >> 9, c = g & 511;
        int h = c >> 7, f = c & 127;
        float s = 0.f;
        #pragma unroll 8
        for (int d = 0; d < 64; ++d)
            s = fmaf(W[f * HD + h * 64 + d], cls_w[(h * 64 + d) * NC + cls], s);
        ws[WS_MT + (size_t)cls * 512 + c] = s;
    }
}

// ei[n][h] = sum_f nodef[n][f] * w_src[h][f]
__global__ void gat_prep_ei(const float* __restrict__ nodef,
                            float* __restrict__ ws, int n_nodes)
{
    const int t = threadIdx.x;
    const int lane = t & 63;
    const int node = blockIdx.x * 64 + (t >> 6) * 16 + (lane >> 2);
    const int q = lane & 3;
    if (node >= n_nodes) return;
    const float* wsrc = ws + WS_WSRC;
    const float4* xp = (const float4*)(nodef + (size_t)node * NF + q * 32);
    float p0 = 0.f, p1 = 0.f, p2 = 0.f, p3 = 0.f;
    #pragma unroll
    for (int j = 0; j < 8; ++j) {
        float4 x  = xp[j];
        float4 w0 = *(const float4*)&wsrc[0 * NF + q * 32 + 4 * j];
        float4 w1 = *(const float4*)&wsrc[1 * NF + q * 32 + 4 * j];
        float4 w2 = *(const float4*)&wsrc[2 * NF + q * 32 + 4 * j];
        float4 w3 = *(const float4*)&wsrc[3 * NF + q * 32 + 4 * j];
        p0 += x.x*w0.x + x.y*w0.y + x.z*w0.z + x.w*w0.w;
        p1 += x.x*w1.x + x.y*w1.y + x.z*w1.z + x.w*w1.w;
        p2 += x.x*w2.x + x.y*w2.y + x.z*w2.z + x.w*w2.w;
        p3 += x.x*w3.x + x.y*w3.y + x.z*w3.z + x.w*w3.w;
    }
    #pragma unroll
    for (int st = 1; st < 4; st <<= 1) {
        p0 += __shfl_xor(p0, st); p1 += __shfl_xor(p1, st);
        p2 += __shfl_xor(p2, st); p3 += __shfl_xor(p3, st);
    }
    if (q == 0)
        *(float4*)&ws[WS_EI + (size_t)node * 4] = make_float4(p0, p1, p2, p3);
}

// Wave-per-node GAT: no block barriers in the node loop. Pass 1 row-sliced
// global reads -> e via in-wave shuffles; pass 2 column-sliced global reads
// (L2-hot re-touch) -> aggregation. 20000 % 32 == 0: no tail guards.
__global__ __launch_bounds__(256, 3)
void gat_main(const float* __restrict__ neigh,
              const float* __restrict__ ws,
              float* __restrict__ out, int n_nodes)
{
    __shared__ __align__(16) unsigned short zlB[NPB2][512];   // 32 KB bf16 z
    __shared__ __align__(16) float alpha_l[WPB][2][KN * NH];  // 4 KB wave-private

    const int t    = threadIdx.x;
    const int w    = t >> 6;
    const int lane = t & 63;
    const int g8   = lane >> 3;      // row-group 0..7 (pass 1)
    const int fq   = lane & 7;       // feature-slice 0..7 (pass 1)
    const float* wdst = ws + WS_WDST;
    const float* MT   = ws + WS_MT;
    const float* ei_g = ws + WS_EI;

    const int node0  = blockIdx.x * NPB2;
    const int nodeW0 = node0 + w * NPW;

    // per-wave register cache of w~dst slices: wd[h][j] = wdst[h*128+fq*4+32j]
    float4 wd[4][4];
    #pragma unroll
    for (int h = 0; h < 4; ++h)
        #pragma unroll
        for (int j = 0; j < 4; ++j)
            wd[h][j] = *(const float4*)&wdst[h * NF + fq * 4 + 32 * j];

    for (int i = 0; i < NPW; ++i) {
        const int node = nodeW0 + i;
        const float* xb = neigh + (size_t)node * (KN * NF);
        const float4 eis = *(const float4*)&ei_g[(size_t)node * 4];  // uniform

        // ---- pass 1: e_j partials, row-sliced (8 lanes x 16B per row chunk) ----
        float ep[4][4];   // [r8][h], row = r8*8 + g8
        #pragma unroll
        for (int r8 = 0; r8 < 4; ++r8) {
            const float4* xr = (const float4*)(xb + (size_t)(r8 * 8 + g8) * NF);
            float4 x0 = xr[fq], x1 = xr[fq + 8], x2 = xr[fq + 16], x3 = xr[fq + 24];
            #pragma unroll
            for (int h = 0; h < 4; ++h) {
                ep[r8][h] =
                    x0.x*wd[h][0].x + x0.y*wd[h][0].y + x0.z*wd[h][0].z + x0.w*wd[h][0].w
                  + x1.x*wd[h][1].x + x1.y*wd[h][1].y + x1.z*wd[h][1].z + x1.w*wd[h][1].w
                  + x2.x*wd[h][2].x + x2.y*wd[h][2].y + x2.z*wd[h][2].z + x2.w*wd[h][2].w
                  + x3.x*wd[h][3].x + x3.y*wd[h][3].y + x3.z*wd[h][3].z + x3.w*wd[h][3].w;
            }
        }
        // reduce over the 8 feature-slices (lanes sharing g8)
        #pragma unroll
        for (int st = 1; st < 8; st <<= 1)
            #pragma unroll
            for (int r8 = 0; r8 < 4; ++r8)
                #pragma unroll
                for (int h = 0; h < 4; ++h)
                    ep[r8][h] += __shfl_xor(ep[r8][h], st);

        // ---- LeakyReLU + exp + per-head sums (no max-sub: |e|max ~ 10) ----
        const float eh[4] = {eis.x, eis.y, eis.z, eis.w};
        float ex[4][4], ssh[4] = {0.f, 0.f, 0.f, 0.f};
        #pragma unroll
        for (int r8 = 0; r8 < 4; ++r8)
            #pragma unroll
            for (int h = 0; h < 4; ++h) {
                float z = eh[h] + ep[r8][h];
                float l = fmaxf(z, 0.2f * z);
                ex[r8][h] = __expf(l);
                ssh[h] += ex[r8][h];
            }
        #pragma unroll
        for (int st = 8; st < 64; st <<= 1)
            #pragma unroll
            for (int h = 0; h < 4; ++h)
                ssh[h] += __shfl_xor(ssh[h], st);
        float inv[4];
        #pragma unroll
        for (int h = 0; h < 4; ++h) inv[h] = 1.f / ssh[h];

        // ---- publish raw exp weights to wave-private alpha buffer ----
        float* al = &alpha_l[w][i & 1][0];
        if (fq == 0) {
            #pragma unroll
            for (int r8 = 0; r8 < 4; ++r8)
                *(float4*)&al[(r8 * 8 + g8) * 4] =
                    make_float4(ex[r8][0], ex[r8][1], ex[r8][2], ex[r8][3]);
        }
        asm volatile("s_waitcnt lgkmcnt(0)" ::: "memory");  // same-wave visibility
        __builtin_amdgcn_sched_barrier(0);

        // ---- pass 2: aggregation, column-sliced (512B coalesced row reads) ----
        float zA[4] = {0.f, 0.f, 0.f, 0.f}, zB[4] = {0.f, 0.f, 0.f, 0.f};
        const float* xcol = xb + lane * 2;
        #pragma unroll 8
        for (int k = 0; k < KN; ++k) {
            float4 a4 = *(const float4*)&al[k * 4];            // LDS broadcast
            float2 x2 = *(const float2*)(xcol + (size_t)k * NF); // L2-hot
            zA[0] = fmaf(a4.x, x2.x, zA[0]); zB[0] = fmaf(a4.x, x2.y, zB[0]);
            zA[1] = fmaf(a4.y, x2.x, zA[1]); zB[1] = fmaf(a4.y, x2.y, zB[1]);
            zA[2] = fmaf(a4.z, x2.x, zA[2]); zB[2] = fmaf(a4.z, x2.y, zB[2]);
            zA[3] = fmaf(a4.w, x2.x, zA[3]); zB[3] = fmaf(a4.w, x2.y, zB[3]);
        }
        unsigned short* zr = zlB[w * NPW + i];
        #pragma unroll
        for (int h = 0; h < 4; ++h) {
            ushort2 p;
            p.x = bf16_of(zA[h] * inv[h]);
            p.y = bf16_of(zB[h] * inv[h]);
            *(ushort2*)&zr[h * NF + lane * 2] = p;
        }
    }
    __syncthreads();   // zl visible; the only block-wide sync

    // ---- fused classifier: y[i][cls] = zl[i][:] . MT[cls][:] ----
    {
        const int cls = t & 63, s = t >> 6;
        float acc[NPB2];
        if (cls < NC) {
            const float4* mp = (const float4*)&MT[(size_t)cls * 512 + s * 128];
            #pragma unroll
            for (int i = 0; i < NPB2; ++i) acc[i] = 0.f;
            #pragma unroll 2
            for (int c4 = 0; c4 < 32; ++c4) {
                float4 mv = mp[c4];
                #pragma unroll
                for (int i = 0; i < NPB2; ++i) {
                    ushort4 zv = *(const ushort4*)&zlB[i][s * 128 + c4 * 4]; // bcast
                    acc[i] += f_of_bf16(zv.x) * mv.x + f_of_bf16(zv.y) * mv.y
                            + f_of_bf16(zv.z) * mv.z + f_of_bf16(zv.w) * mv.w;
                }
            }
        }
        __syncthreads();                       // all zl reads done
        float* ypart = (float*)&zlB[0][0];     // overlay scratch (20 KB < 32 KB)
        if (cls < NC) {
            #pragma unroll
            for (int i = 0; i < NPB2; ++i)
                ypart[s * (NPB2 * NC) + i * NC + cls] = acc[i];
        }
        __syncthreads();
        #pragma unroll
        for (int rep = 0; rep < 5; ++rep) {
            int p = t + rep * 256;
            if (p < NPB2 * NC) {
                float y = ypart[p] + ypart[NPB2 * NC + p]
                        + ypart[2 * NPB2 * NC + p] + ypart[3 * NPB2 * NC + p];
                out[(size_t)node0 * NC + p] = y;   // coalesced
            }
        }
    }
}

extern "C" void kernel_launch(void* const* d_in, const int* in_sizes, int n_in,
                              void* d_out, int out_size, void* d_ws, size_t ws_size,
                              hipStream_t stream) {
    const float* nodef = (const float*)d_in[0];
    const float* neigh = (const float*)d_in[1];
    const float* W     = (const float*)d_in[2];
    const float* a_src = (const float*)d_in[3];
    const float* a_dst = (const float*)d_in[4];
    const float* cls_w = (const float*)d_in[5];
    float* out = (float*)d_out;
    float* ws  = (float*)d_ws;

    const int n_nodes = in_sizes[0] / NF;   // 20000 (divisible by 32)

    hipLaunchKernelGGL(gat_prep_wm, dim3(4 + (NC * 512 + 255) / 256), dim3(256), 0, stream,
                       W, a_src, a_dst, cls_w, ws);
    hipLaunchKernelGGL(gat_prep_ei, dim3((n_nodes + 63) / 64), dim3(256), 0, stream,
                       nodef, ws, n_nodes);
    hipLaunchKernelGGL(gat_main, dim3(n_nodes / NPB2), dim3(256), 0, stream,
                       neigh, ws, out, n_nodes);
}

// Round 13
// 126.292 us; speedup vs baseline: 1.4120x; 1.4120x over previous
//
#include <hip/hip_runtime.h>

#define KN 32      // neighbors
#define NF 128     // feature dim
#define NH 4       // heads
#define HD 256     // H*D
#define NC 40      // classes
#define NPB 8      // nodes per block
#define XSS 132    // Xs row stride (floats)

// ws layout (floats): [0,512)=w_src[h][f], [512,1024)=w_dst[h][f],
//   [1024,21504)=MT[cls][h*128+f]
#define WS_WSRC 0
#define WS_WDST 512
#define WS_MT   1024

// merged prep: blocks 0-3 -> w_src/w_dst; blocks 4.. -> MT
__global__ void gat_prep_wm(const float* __restrict__ W,
                            const float* __restrict__ a_src,
                            const float* __restrict__ a_dst,
                            const float* __restrict__ cls_w,
                            float* __restrict__ ws)
{
    if (blockIdx.x < 4) {
        int g = blockIdx.x * 256 + threadIdx.x;
        int which = g >> 9, h = (g >> 7) & 3, f = g & 127;
        const float* a = which ? a_dst : a_src;
        float s = 0.f;
        #pragma unroll 8
        for (int d = 0; d < 64; ++d)
            s = fmaf(W[f * HD + h * 64 + d], a[h * 64 + d], s);
        ws[g] = s;
    } else {
        int g = (blockIdx.x - 4) * 256 + threadIdx.x;
        if (g >= NC * 512) return;
        int cls = g >> 9, c = g & 511;
        int h = c >> 7, f = c & 127;
        float s = 0.f;
        #pragma unroll 8
        for (int d = 0; d < 64; ++d)
            s = fmaf(W[f * HD + h * 64 + d], cls_w[(h * 64 + d) * NC + cls], s);
        ws[WS_MT + (size_t)cls * 512 + c] = s;
    }
}

// LDS-only barrier: waits DS ops, does NOT drain vmcnt -> prefetch loads
// stay in flight across it.
static __device__ __forceinline__ void lds_barrier() {
    __builtin_amdgcn_sched_barrier(0);
    asm volatile("s_waitcnt lgkmcnt(0)");
    __builtin_amdgcn_sched_barrier(0);
    __builtin_amdgcn_s_barrier();
    __builtin_amdgcn_sched_barrier(0);
}

__global__ __launch_bounds__(256, 3)
void gat_main(const float* __restrict__ nodef,
              const float* __restrict__ neigh,
              const float* __restrict__ ws,
              float* __restrict__ out, int n_nodes)
{
    __shared__ __align__(16) float Xs[2][KN * XSS];   // 33.8 KB dbuf tile
    __shared__ __align__(16) float zl[NPB][512];      // 16 KB aggregated feats
    __shared__ __align__(16) float e_lds[2][NH * KN]; // 1 KB dbuf logits
    __shared__ __align__(16) float ei_lds[NPB][NH];   // 128 B center logits

    const int t    = threadIdx.x;
    const int lane = t & 63;
    const int kq   = t >> 3;        // neighbor row 0..31
    const int fq   = t & 7;         // feature-slice id
    const int wv   = t >> 6;        // wave id == head in agg phase
    const float* wsrc = ws + WS_WSRC;
    const float* wdst = ws + WS_WDST;
    const float* MT   = ws + WS_MT;

    const int node0 = blockIdx.x * NPB;
    if (node0 >= n_nodes) return;

    // ---- block-local e_i: node i2 = t>>5, 32 threads per node ----
    // visibility: written before body-0's barrier, read only after it.
    {
        const int i2 = t >> 5, sub = t & 31;
        float4 x = ((const float4*)(nodef + (size_t)(node0 + i2) * NF))[sub];
        float4 w0 = *(const float4*)&wsrc[0 * NF + sub * 4];
        float4 w1 = *(const float4*)&wsrc[1 * NF + sub * 4];
        float4 w2 = *(const float4*)&wsrc[2 * NF + sub * 4];
        float4 w3 = *(const float4*)&wsrc[3 * NF + sub * 4];
        float p0 = x.x*w0.x + x.y*w0.y + x.z*w0.z + x.w*w0.w;
        float p1 = x.x*w1.x + x.y*w1.y + x.z*w1.z + x.w*w1.w;
        float p2 = x.x*w2.x + x.y*w2.y + x.z*w2.z + x.w*w2.w;
        float p3 = x.x*w3.x + x.y*w3.y + x.z*w3.z + x.w*w3.w;
        #pragma unroll
        for (int st = 1; st < 32; st <<= 1) {
            p0 += __shfl_xor(p0, st); p1 += __shfl_xor(p1, st);
            p2 += __shfl_xor(p2, st); p3 += __shfl_xor(p3, st);
        }
        if (sub == 0)
            *(float4*)&ei_lds[i2][0] = make_float4(p0, p1, p2, p3);
    }

    // register-cached w~dst slices
    float4 wd[4][4];
    #pragma unroll
    for (int h = 0; h < 4; ++h)
        #pragma unroll
        for (int j = 0; j < 4; ++j)
            wd[h][j] = *(const float4*)&wdst[h * NF + fq * 4 + 32 * j];

    // prologue: depth-3 prefetch (nodes 0,1,2 into sets 0,1,2)
    float4 xv[3][4];
    #pragma unroll
    for (int s = 0; s < 3; ++s) {
        const float4* src = (const float4*)(neigh + ((size_t)(node0 + s) * KN + kq) * NF);
        #pragma unroll
        for (int j = 0; j < 4; ++j) xv[s][j] = src[fq + 8 * j];
    }

    #pragma unroll
    for (int i = 0; i < NPB; ++i) {
        const int set = i % 3;        // compile-time after full unroll
        const int buf = i & 1;

        // stage tile into this parity's LDS buffer
        #pragma unroll
        for (int j = 0; j < 4; ++j)
            *(float4*)&Xs[buf][kq * XSS + fq * 4 + 32 * j] = xv[set][j];

        // e_j partial dots from registers
        float s0 = 0.f, s1 = 0.f, s2 = 0.f, s3 = 0.f;
        #pragma unroll
        for (int j = 0; j < 4; ++j) {
            float4 x = xv[set][j];
            s0 += x.x*wd[0][j].x + x.y*wd[0][j].y + x.z*wd[0][j].z + x.w*wd[0][j].w;
            s1 += x.x*wd[1][j].x + x.y*wd[1][j].y + x.z*wd[1][j].z + x.w*wd[1][j].w;
            s2 += x.x*wd[2][j].x + x.y*wd[2][j].y + x.z*wd[2][j].z + x.w*wd[2][j].w;
            s3 += x.x*wd[3][j].x + x.y*wd[3][j].y + x.z*wd[3][j].z + x.w*wd[3][j].w;
        }

        // depth-3 prefetch: set is dead, reload with node i+3
        if (i + 3 < NPB) {
            const float4* src = (const float4*)(neigh + ((size_t)(node0 + i + 3) * KN + kq) * NF);
            #pragma unroll
            for (int j = 0; j < 4; ++j) xv[set][j] = src[fq + 8 * j];
        }

        // reduce e_j over the 8 feature-slices
        #pragma unroll
        for (int st = 1; st < 8; st <<= 1) {
            s0 += __shfl_xor(s0, st); s1 += __shfl_xor(s1, st);
            s2 += __shfl_xor(s2, st); s3 += __shfl_xor(s3, st);
        }
        if (fq == 0) {                       // 32 writers -> 32 distinct banks
            e_lds[buf][0 * KN + kq] = s0; e_lds[buf][1 * KN + kq] = s1;
            e_lds[buf][2 * KN + kq] = s2; e_lds[buf][3 * KN + kq] = s3;
        }

        lds_barrier();     // e + tile visible; prefetch NOT drained

        // fused softmax + aggregation; thread owns (head=wv, cols 2l,2l+1)
        // b64 reads: lanes 0-15 cover all 32 banks, 2-way alias = free.
        const float ei_h = ei_lds[i][wv];    // wave-uniform broadcast
        float ss = 0.f, zx = 0.f, zy = 0.f;
        #pragma unroll
        for (int m = 0; m < 8; ++m) {
            float4 evm = *(const float4*)&e_lds[buf][wv * KN + m * 4]; // bcast
            float el[4] = {evm.x, evm.y, evm.z, evm.w};
            #pragma unroll
            for (int kk = 0; kk < 4; ++kk) {
                float z_ = ei_h + el[kk];
                float l_ = fmaxf(z_, 0.2f * z_);       // LeakyReLU
                float p_ = __expf(l_);
                ss += p_;
                float2 x2 = *(const float2*)&Xs[buf][(m * 4 + kk) * XSS + 2 * lane];
                zx = fmaf(p_, x2.x, zx);
                zy = fmaf(p_, x2.y, zy);
            }
        }
        float inv = 1.f / ss;
        *(float2*)&zl[i][wv * NF + 2 * lane] = make_float2(zx * inv, zy * inv);
    }
    __syncthreads();   // full drain once per block - zl visible

    // ---- fused classifier: y[i][cls] = zl[i][:] . MT[cls][:] ----
    float* ypart = &Xs[0][0];   // Xs dead; ypart[s][i][cls]
    {
        int cls = t & 63, s = t >> 6;
        if (cls < NC) {
            const float4* mp = (const float4*)&MT[(size_t)cls * 512 + s * 128];
            float acc[NPB];
            #pragma unroll
            for (int i = 0; i < NPB; ++i) acc[i] = 0.f;
            #pragma unroll 2
            for (int c4 = 0; c4 < 32; ++c4) {
                float4 mv = mp[c4];
                #pragma unroll
                for (int i = 0; i < NPB; ++i) {
                    float4 zv = *(const float4*)&zl[i][s * 128 + c4 * 4];  // bcast
                    acc[i] += zv.x * mv.x + zv.y * mv.y + zv.z * mv.z + zv.w * mv.w;
                }
            }
            #pragma unroll
            for (int i = 0; i < NPB; ++i)
                ypart[s * (NPB * NC) + i * NC + cls] = acc[i];
        }
    }
    __syncthreads();
    #pragma unroll
    for (int rep = 0; rep < 2; ++rep) {
        int p = t + rep * 256;
        if (p < NPB * NC) {
            float y = ypart[p] + ypart[NPB * NC + p]
                    + ypart[2 * NPB * NC + p] + ypart[3 * NPB * NC + p];
            out[(size_t)node0 * NC + p] = y;   // consecutive -> coalesced
        }
    }
}

extern "C" void kernel_launch(void* const* d_in, const int* in_sizes, int n_in,
                              void* d_out, int out_size, void* d_ws, size_t ws_size,
                              hipStream_t stream) {
    const float* nodef = (const float*)d_in[0];
    const float* neigh = (const float*)d_in[1];
    const float* W     = (const float*)d_in[2];
    const float* a_src = (const float*)d_in[3];
    const float* a_dst = (const float*)d_in[4];
    const float* cls_w = (const float*)d_in[5];
    float* out = (float*)d_out;
    float* ws  = (float*)d_ws;

    const int n_nodes = in_sizes[0] / NF;   // 20000

    hipLaunchKernelGGL(gat_prep_wm, dim3(4 + (NC * 512 + 255) / 256), dim3(256), 0, stream,
                       W, a_src, a_dst, cls_w, ws);
    hipLaunchKernelGGL(gat_main, dim3((n_nodes + NPB - 1) / NPB), dim3(256), 0, stream,
                       nodef, neigh, ws, out, n_nodes);
}